// Round 17
// baseline (72.039 us; speedup 1.0000x reference)
//
#include <hip/hip_runtime.h>
#include <math.h>

// ============================================================================
// ROUND 17 = TIMING PROBE (resubmit of round 16; infra failure).
// Kernels byte-identical to round 15. kernel_launch launches radial_bin_csr
// 4x (idempotent) + gather 1x. bin_cost ~= (total - 33.95)/3.
// ============================================================================

// Problem constants (fixed by the reference setup)
#define NB     32
#define NA     1024
#define NTYPE  4
#define NWAVE  16
#define PPB    65536               // pairs per batch
#define NPAIRS (NB * PPB)          // 2,097,152 pairs
#define TOTATOM (NB * NA)          // 32768
#define DENS_ELEMS (TOTATOM * NTYPE * NWAVE)  // == out_size
#define CUTOFF      5.0f
#define CUTOFF_INV  0.2f
#define PI_F 3.14159265358979323846f

#define NSPLIT 8                   // bin blocks per batch
#define BLOCK_A 1024
#define PPBLK (PPB / NSPLIT)       // 8192 pairs per bin-block
#define KITERS_A (PPBLK / BLOCK_A) // 8
#define NSEG (NB * NSPLIT)         // 256 CSR segments
#define ENC_SCALE (65535.0f / CUTOFF)
#define DEC_SCALE (CUTOFF / 65535.0f)
#define FC_ENC 65535.0f
#define FC_DEC (1.0f / 65535.0f)

#define CSR_BYTES  ((size_t)NSEG * PPBLK * 4)        // 8 MiB (packed u32)
#define OFFS_U32S  ((size_t)NSEG * (NA + 1))         // 262,400
#define WS2_NEEDED (CSR_BYTES + OFFS_U32S * 4)       // ~9.4 MB

// Gather geometry: 8 threads/atom, 2 waves each.
#define GBLOCK 256
#define APB    32                  // atoms per gather block
#define ACAP   129                 // odd stride -> conflict-free ds_read_b64

// Compiler-visible native LDS u32 atomic add (returns old).
typedef __attribute__((address_space(3))) unsigned lds_u32;
__device__ __forceinline__ unsigned lds_uinc(unsigned* p) {
    lds_u32* lp = (lds_u32*)(unsigned)(unsigned long long)p;
    return __atomic_fetch_add(lp, 1u, __ATOMIC_RELAXED);
}

// ---------------------------------------------------------------------------
// Phase A (identical to round 15).
// ---------------------------------------------------------------------------
__global__ __launch_bounds__(BLOCK_A) void radial_bin_csr(
    const float* __restrict__ coords,      // [TOTATOM*3]
    const float* __restrict__ shifts,      // [NPAIRS*3]
    const int*   __restrict__ atom_index,  // [NB*2*PPB]
    unsigned*    __restrict__ csr,         // [NSEG][PPBLK] packed
    unsigned*    __restrict__ offs)        // [NSEG][NA+1]
{
    __shared__ unsigned hist[NA];            // 4 KiB
    __shared__ unsigned base[NA + 1];        // 4 KiB
    __shared__ unsigned wsum[16];
    __shared__ unsigned scsr[PPBLK];         // 32 KiB

    const int b    = blockIdx.x >> 3;        // / NSPLIT
    const int s    = blockIdx.x & (NSPLIT - 1);
    const int seg  = b * NSPLIT + s;
    const int tid  = threadIdx.x;
    const int lane = tid & 63;
    const int wid  = tid >> 6;

    hist[tid] = 0u;
    __syncthreads();

    const int* ai0 = atom_index + (b * 2 + 0) * PPB + s * PPBLK;
    const int* ai1 = atom_index + (b * 2 + 1) * PPB + s * PPBLK;
    const float* cb  = coords + (size_t)b * NA * 3;
    const float* shb = shifts + ((size_t)b * PPB + s * PPBLK) * 3;

    int      ik[KITERS_A];   // center atom, -1 if dropped
    unsigned rk[KITERS_A];   // rank from histogram atomic
    unsigned ek[KITERS_A];   // packed (fc_u16 << 16) | r_u16

    #pragma unroll
    for (int k = 0; k < KITERS_A; ++k) {
        const int pp = k * BLOCK_A + tid;
        const int i = ai0[pp];
        const int j = ai1[pp];

        const float sx = shb[pp * 3 + 0];
        const float sy = shb[pp * 3 + 1];
        const float sz = shb[pp * 3 + 2];
        const bool valid = (sx > -1e9f) && (sy > -1e9f) && (sz > -1e9f);

        const float dx = cb[i * 3 + 0] - cb[j * 3 + 0] + sx;
        const float dy = cb[i * 3 + 1] - cb[j * 3 + 1] + sy;
        const float dz = cb[i * 3 + 2] - cb[j * 3 + 2] + sz;
        const float r  = sqrtf(dx * dx + dy * dy + dz * dz);

        // r >= CUTOFF -> fc == 0 exactly: drop. invalid -> drop.
        if (valid && r < CUTOFF) {
            const unsigned rank = lds_uinc(&hist[i]);   // ds_add_rtn_u32
            unsigned e = (unsigned)(r * ENC_SCALE + 0.5f);
            if (e > 65535u) e = 65535u;
            const float fc = 0.5f * (__cosf(r * (PI_F * CUTOFF_INV)) + 1.0f);
            unsigned fq = (unsigned)(fc * FC_ENC + 0.5f);
            if (fq > 65535u) fq = 65535u;
            ik[k] = i;
            rk[k] = rank;
            ek[k] = (fq << 16) | e;
        } else {
            ik[k] = -1;
            rk[k] = 0u;
            ek[k] = 0u;
        }
    }
    __syncthreads();

    // Block-wide exclusive prefix scan of hist[1024].
    const unsigned h = hist[tid];
    unsigned x = h;
    #pragma unroll
    for (int d = 1; d < 64; d <<= 1) {
        const unsigned v = __shfl_up(x, d);
        if (lane >= d) x += v;
    }
    if (lane == 63) wsum[wid] = x;
    __syncthreads();
    if (tid < 16) {
        const unsigned own = wsum[tid];
        unsigned y = own;
        #pragma unroll
        for (int d = 1; d < 16; d <<= 1) {
            const unsigned v = __shfl_up(y, d);
            if (lane >= d) y += v;
        }
        wsum[tid] = y - own;     // exclusive wave prefix
    }
    __syncthreads();
    const unsigned incl = x + wsum[wid];
    base[tid] = incl - h;
    if (tid == BLOCK_A - 1) base[NA] = incl;
    __syncthreads();

    // Pass 2: place each pair at base[atom] + rank inside LDS CSR.
    #pragma unroll
    for (int k = 0; k < KITERS_A; ++k) {
        if (ik[k] >= 0) {
            scsr[base[ik[k]] + rk[k]] = ek[k];
        }
    }
    __syncthreads();

    // Stream out coalesced.
    {
        const uint4* src = reinterpret_cast<const uint4*>(scsr);
        uint4* dst = reinterpret_cast<uint4*>(csr + (size_t)seg * PPBLK);
        #pragma unroll
        for (int k = 0; k < PPBLK / 4 / BLOCK_A; ++k)
            dst[k * BLOCK_A + tid] = src[k * BLOCK_A + tid];
    }
    unsigned* og = offs + (size_t)seg * (NA + 1);
    og[tid] = base[tid];
    if (tid == 0) og[NA] = base[NA];
}

// ---------------------------------------------------------------------------
// Phase B (identical to round 15).
// ---------------------------------------------------------------------------
__global__ __launch_bounds__(GBLOCK) void radial_gather_staged8(
    const unsigned* __restrict__ csr,    // [NSEG][PPBLK] packed
    const unsigned* __restrict__ offs,   // [NSEG][NA+1]
    const float* __restrict__ rs,        // [NTYPE*NWAVE]
    const float* __restrict__ inta,      // [NTYPE*NWAVE]
    const int*   __restrict__ species,   // [TOTATOM]
    float*       __restrict__ out)       // [TOTATOM][NTYPE*NWAVE]
{
    __shared__ float2   sdata[APB * ACAP];   // 32.25 KiB decoded entries
    __shared__ unsigned scnt[APB];

    const int tid = threadIdx.x;
    const int g0  = blockIdx.x * APB;        // first atom of block
    const int b   = g0 >> 10;                // batch (blocks never cross batches)

    // ---- Staging: all 256 threads -> (at, s), at in 0..31, s in 0..7 ----
    {
        const int at = tid >> 3;
        const int s  = tid & 7;
        const int a  = (g0 + at) & (NA - 1);
        const int seg = b * NSPLIT + s;
        const unsigned* ob = offs + (size_t)seg * (NA + 1) + a;
        const unsigned lo = ob[0];
        const unsigned c  = ob[1] - lo;

        // inclusive scan of c over the 8 segment-lanes of this atom
        unsigned x = c;
        #pragma unroll
        for (int d = 1; d < 8; d <<= 1) {
            const unsigned v = __shfl_up(x, d, 8);
            if ((tid & 7) >= d) x += v;
        }
        const unsigned pfx = x - c;          // exclusive prefix
        if ((tid & 7) == 7) scnt[at] = (x < ACAP) ? x : ACAP;

        const unsigned* bp = csr + (size_t)seg * PPBLK + lo;
        float2* dst = sdata + at * ACAP;
        for (unsigned k = 0; k < c; ++k) {
            const unsigned p = pfx + k;
            if (p < ACAP) {
                const unsigned v = bp[k];
                float2 e;
                e.x = (float)(v & 0xFFFFu) * DEC_SCALE;   // r
                e.y = (float)(v >> 16) * FC_DEC;          // fc
                dst[p] = e;
            }
        }
    }
    __syncthreads();

    // ---- Compute: (at, w-pair) : w0 = 2*(tid&7), w1 = w0+1 ----
    const int at = tid >> 3;
    const int w0 = (tid & 7) << 1;
    const int g  = g0 + at;
    const int spec = species[g];

    const float rs0 = rs[(spec << 4) + w0];
    const float rs1 = rs[(spec << 4) + w0 + 1];
    const float ia0 = -10.0f * inta[(spec << 4) + w0];
    const float ia1 = -10.0f * inta[(spec << 4) + w0 + 1];
    const int n = (int)scnt[at];
    const float2* sp = sdata + at * ACAP;

    float acc0 = 0.0f, acc1 = 0.0f;
    for (int k = 0; k < n; ++k) {
        const float2 e = sp[k];              // 8-lane same-address broadcast
        const float d0 = e.x - rs0;
        const float d1 = e.x - rs1;
        acc0 = fmaf(e.y, __expf(ia0 * d0 * d0), acc0);
        acc1 = fmaf(e.y, __expf(ia1 * d1 * d1), acc1);
    }

    const float2 sq = make_float2(acc0 * acc0, acc1 * acc1);
    const float2 zero = make_float2(0.f, 0.f);
    float* orow = out + (size_t)g * (NTYPE * NWAVE) + w0;
    #pragma unroll
    for (int ty = 0; ty < NTYPE; ++ty)
        *reinterpret_cast<float2*>(orow + ty * NWAVE) = (ty == spec) ? sq : zero;
}

// ---------------------------------------------------------------------------
// Fallback path (ws too small): global-atomic version (no workspace needed).
// ---------------------------------------------------------------------------
__global__ __launch_bounds__(256) void radial_pair_atomic(
    const float* __restrict__ coords, const float* __restrict__ shifts,
    const float* __restrict__ rs, const float* __restrict__ inta,
    const int* __restrict__ atom_index, const int* __restrict__ species,
    float* __restrict__ dens)
{
    int p = blockIdx.x * blockDim.x + threadIdx.x;
    if (p >= NPAIRS) return;
    int b  = p >> 16;
    int pp = p & (PPB - 1);
    int i = atom_index[(b * 2 + 0) * PPB + pp] + b * NA;
    int j = atom_index[(b * 2 + 1) * PPB + pp] + b * NA;
    float sx = shifts[p * 3 + 0], sy = shifts[p * 3 + 1], sz = shifts[p * 3 + 2];
    bool valid = (sx > -1e9f) && (sy > -1e9f) && (sz > -1e9f);
    float dx = coords[i * 3 + 0] - coords[j * 3 + 0] + sx;
    float dy = coords[i * 3 + 1] - coords[j * 3 + 1] + sy;
    float dz = coords[i * 3 + 2] - coords[j * 3 + 2] + sz;
    float r  = sqrtf(dx * dx + dy * dy + dz * dz);
    int spec = species[i];
    float x  = fminf(r * CUTOFF_INV, 1.0f);
    float fc = 0.5f * (__cosf(x * PI_F) + 1.0f);
    if (!valid) fc = 0.0f;
    const float* rsrow   = rs   + spec * NWAVE;
    const float* intarow = inta + spec * NWAVE;
    float* dst = dens + ((size_t)i * NTYPE + spec) * NWAVE;
    #pragma unroll
    for (int w = 0; w < NWAVE; ++w) {
        float d   = r - rsrow[w];
        float val = fc * __expf(-10.0f * intarow[w] * d * d);
        atomicAdd(dst + w, val);
    }
}

__global__ __launch_bounds__(256) void square_kernel(float* __restrict__ out)
{
    int i = blockIdx.x * blockDim.x + threadIdx.x;
    if (i * 4 >= DENS_ELEMS) return;
    float4* p = reinterpret_cast<float4*>(out) + i;
    float4 v = *p;
    v.x *= v.x; v.y *= v.y; v.z *= v.z; v.w *= v.w;
    *p = v;
}

extern "C" void kernel_launch(void* const* d_in, const int* in_sizes, int n_in,
                              void* d_out, int out_size, void* d_ws, size_t ws_size,
                              hipStream_t stream) {
    const float* coords     = (const float*)d_in[0];
    const float* shifts     = (const float*)d_in[1];
    const float* rs         = (const float*)d_in[2];
    const float* inta       = (const float*)d_in[3];
    const int*   atom_index = (const int*)d_in[6];
    const int*   species    = (const int*)d_in[7];
    float* out = (float*)d_out;

    if (ws_size >= WS2_NEEDED) {
        unsigned* csr  = (unsigned*)d_ws;
        unsigned* offs = (unsigned*)((char*)d_ws + CSR_BYTES);

        // PROBE: bin launched 4x (idempotent; identical output each time).
        // bin_marginal_cost ~= (total_this_round - 33.95us) / 3.
        #pragma unroll
        for (int rep = 0; rep < 4; ++rep) {
            radial_bin_csr<<<dim3(NSEG), dim3(BLOCK_A), 0, stream>>>(
                coords, shifts, atom_index, csr, offs);
        }
        radial_gather_staged8<<<dim3(TOTATOM / APB), dim3(GBLOCK), 0, stream>>>(
            csr, offs, rs, inta, species, out);
    } else {
        hipMemsetAsync(d_out, 0, (size_t)DENS_ELEMS * sizeof(float), stream);
        radial_pair_atomic<<<dim3((NPAIRS + 255) / 256), dim3(256), 0, stream>>>(
            coords, shifts, rs, inta, atom_index, species, out);
        square_kernel<<<dim3((DENS_ELEMS / 4 + 255) / 256), dim3(256), 0, stream>>>(out);
    }
}

// Round 19
// 38.287 us; speedup vs baseline: 1.8815x; 1.8815x over previous
//
#include <hip/hip_runtime.h>
#include <math.h>

// Problem constants (fixed by the reference setup)
#define NB     32
#define NA     1024
#define NTYPE  4
#define NWAVE  16
#define PPB    65536               // pairs per batch
#define NPAIRS (NB * PPB)          // 2,097,152 pairs
#define TOTATOM (NB * NA)          // 32768
#define DENS_ELEMS (TOTATOM * NTYPE * NWAVE)  // == out_size
#define CUTOFF      5.0f
#define CUTOFF_INV  0.2f
#define PI_F 3.14159265358979323846f

#define NSPLIT 8                   // bin blocks per batch
#define BLOCK_A 1024
#define PPBLK (PPB / NSPLIT)       // 8192 pairs per bin-block
#define KITERS_A (PPBLK / BLOCK_A) // 8
#define NSEG (NB * NSPLIT)         // 256 CSR segments
#define ENC_SCALE (65535.0f / CUTOFF)
#define DEC_SCALE (CUTOFF / 65535.0f)
#define FC_ENC 65535.0f
#define FC_DEC (1.0f / 65535.0f)

#define CSR_BYTES  ((size_t)NSEG * PPBLK * 4)        // 8 MiB (packed u32)
#define OFFS_U32S  ((size_t)NSEG * (NA + 1))         // 262,400
#define WS2_NEEDED (CSR_BYTES + OFFS_U32S * 4)       // ~9.4 MB

// Gather geometry: 32 consecutive atoms/block, 8 threads (w-pairs)/atom.
#define GBLOCK 256
#define APB    32
#define SLAB_CAP 2432              // words; block mean ~1962, sd ~44 (+10 sd)

// Compiler-visible native LDS u32 atomic add (returns old).
typedef __attribute__((address_space(3))) unsigned lds_u32;
__device__ __forceinline__ unsigned lds_uinc(unsigned* p) {
    lds_u32* lp = (lds_u32*)(unsigned)(unsigned long long)p;
    return __atomic_fetch_add(lp, 1u, __ATOMIC_RELAXED);
}

// ---------------------------------------------------------------------------
// Phase A (identical to round 15): r + fc once per pair; LDS histogram rank;
// block prefix-scan -> exact CSR (sorted by atom within segment); coalesced out.
// ---------------------------------------------------------------------------
__global__ __launch_bounds__(BLOCK_A) void radial_bin_csr(
    const float* __restrict__ coords,      // [TOTATOM*3]
    const float* __restrict__ shifts,      // [NPAIRS*3]
    const int*   __restrict__ atom_index,  // [NB*2*PPB]
    unsigned*    __restrict__ csr,         // [NSEG][PPBLK] packed
    unsigned*    __restrict__ offs)        // [NSEG][NA+1]
{
    __shared__ unsigned hist[NA];            // 4 KiB
    __shared__ unsigned base[NA + 1];        // 4 KiB
    __shared__ unsigned wsum[16];
    __shared__ unsigned scsr[PPBLK];         // 32 KiB

    const int b    = blockIdx.x >> 3;        // / NSPLIT
    const int s    = blockIdx.x & (NSPLIT - 1);
    const int seg  = b * NSPLIT + s;
    const int tid  = threadIdx.x;
    const int lane = tid & 63;
    const int wid  = tid >> 6;

    hist[tid] = 0u;
    __syncthreads();

    const int* ai0 = atom_index + (b * 2 + 0) * PPB + s * PPBLK;
    const int* ai1 = atom_index + (b * 2 + 1) * PPB + s * PPBLK;
    const float* cb  = coords + (size_t)b * NA * 3;
    const float* shb = shifts + ((size_t)b * PPB + s * PPBLK) * 3;

    int      ik[KITERS_A];   // center atom, -1 if dropped
    unsigned rk[KITERS_A];   // rank from histogram atomic
    unsigned ek[KITERS_A];   // packed (fc_u16 << 16) | r_u16

    #pragma unroll
    for (int k = 0; k < KITERS_A; ++k) {
        const int pp = k * BLOCK_A + tid;
        const int i = ai0[pp];
        const int j = ai1[pp];

        const float sx = shb[pp * 3 + 0];
        const float sy = shb[pp * 3 + 1];
        const float sz = shb[pp * 3 + 2];
        const bool valid = (sx > -1e9f) && (sy > -1e9f) && (sz > -1e9f);

        const float dx = cb[i * 3 + 0] - cb[j * 3 + 0] + sx;
        const float dy = cb[i * 3 + 1] - cb[j * 3 + 1] + sy;
        const float dz = cb[i * 3 + 2] - cb[j * 3 + 2] + sz;
        const float r  = sqrtf(dx * dx + dy * dy + dz * dz);

        // r >= CUTOFF -> fc == 0 exactly: drop. invalid -> drop.
        if (valid && r < CUTOFF) {
            const unsigned rank = lds_uinc(&hist[i]);   // ds_add_rtn_u32
            unsigned e = (unsigned)(r * ENC_SCALE + 0.5f);
            if (e > 65535u) e = 65535u;
            const float fc = 0.5f * (__cosf(r * (PI_F * CUTOFF_INV)) + 1.0f);
            unsigned fq = (unsigned)(fc * FC_ENC + 0.5f);
            if (fq > 65535u) fq = 65535u;
            ik[k] = i;
            rk[k] = rank;
            ek[k] = (fq << 16) | e;
        } else {
            ik[k] = -1;
            rk[k] = 0u;
            ek[k] = 0u;
        }
    }
    __syncthreads();

    // Block-wide exclusive prefix scan of hist[1024].
    const unsigned h = hist[tid];
    unsigned x = h;
    #pragma unroll
    for (int d = 1; d < 64; d <<= 1) {
        const unsigned v = __shfl_up(x, d);
        if (lane >= d) x += v;
    }
    if (lane == 63) wsum[wid] = x;
    __syncthreads();
    if (tid < 16) {
        const unsigned own = wsum[tid];
        unsigned y = own;
        #pragma unroll
        for (int d = 1; d < 16; d <<= 1) {
            const unsigned v = __shfl_up(y, d);
            if (lane >= d) y += v;
        }
        wsum[tid] = y - own;     // exclusive wave prefix
    }
    __syncthreads();
    const unsigned incl = x + wsum[wid];
    base[tid] = incl - h;
    if (tid == BLOCK_A - 1) base[NA] = incl;
    __syncthreads();

    // Pass 2: place each pair at base[atom] + rank inside LDS CSR.
    #pragma unroll
    for (int k = 0; k < KITERS_A; ++k) {
        if (ik[k] >= 0) {
            scsr[base[ik[k]] + rk[k]] = ek[k];
        }
    }
    __syncthreads();

    // Stream out coalesced.
    {
        const uint4* src = reinterpret_cast<const uint4*>(scsr);
        uint4* dst = reinterpret_cast<uint4*>(csr + (size_t)seg * PPBLK);
        #pragma unroll
        for (int k = 0; k < PPBLK / 4 / BLOCK_A; ++k)
            dst[k * BLOCK_A + tid] = src[k * BLOCK_A + tid];
    }
    unsigned* og = offs + (size_t)seg * (NA + 1);
    og[tid] = base[tid];
    if (tid == 0) og[NA] = base[NA];
}

// ---------------------------------------------------------------------------
// Phase B: slab gather. The block's 32 consecutive atoms occupy ONE contiguous
// run per segment in the CSR -> bulk coalesced copy (no scatter, no decode,
// no divergence) into an LDS slab; compute walks 8 LDS sub-ranges per atom.
// ---------------------------------------------------------------------------
__global__ __launch_bounds__(GBLOCK) void radial_gather_slab(
    const unsigned* __restrict__ csr,    // [NSEG][PPBLK] packed
    const unsigned* __restrict__ offs,   // [NSEG][NA+1]
    const float* __restrict__ rs,        // [NTYPE*NWAVE]
    const float* __restrict__ inta,      // [NTYPE*NWAVE]
    const int*   __restrict__ species,   // [TOTATOM]
    float*       __restrict__ out)       // [TOTATOM][NTYPE*NWAVE]
{
    __shared__ unsigned slab[SLAB_CAP];          // 9.5 KiB raw entries
    __shared__ unsigned sofs[NSPLIT][APB + 1];   // 1.03 KiB
    __shared__ unsigned runbase[NSPLIT];

    const int tid = threadIdx.x;
    const int g0  = blockIdx.x * APB;        // first atom of block
    const int b   = g0 >> 10;                // batch (APB | NA -> no crossing)
    const int a0  = g0 & (NA - 1);

    // ---- Load the 8x33 offset window (coalesced) ----
    for (int idx = tid; idx < NSPLIT * (APB + 1); idx += GBLOCK) {
        const int s = idx / (APB + 1);
        const int a = idx - s * (APB + 1);
        sofs[s][a] = offs[(size_t)(b * NSPLIT + s) * (NA + 1) + a0 + a];
    }
    __syncthreads();

    if (tid == 0) {
        unsigned acc = 0;
        #pragma unroll
        for (int s = 0; s < NSPLIT; ++s) {
            runbase[s] = acc;
            acc += sofs[s][APB] - sofs[s][0];
        }
    }
    __syncthreads();

    // ---- Bulk copy: 8 thread-groups of 32, one contiguous run each ----
    {
        const int s = tid >> 5;              // seg
        const int l = tid & 31;
        const unsigned lo  = sofs[s][0];
        const unsigned len = sofs[s][APB] - lo;
        const unsigned* src = csr + (size_t)(b * NSPLIT + s) * PPBLK + lo;
        const unsigned bse = runbase[s];
        for (unsigned k = l; k < len; k += 32) {
            const unsigned p = bse + k;
            if (p < SLAB_CAP) slab[p] = src[k];
        }
    }
    __syncthreads();

    // ---- Compute: thread = (atom, w-pair) ----
    const int at = tid >> 3;                 // 0..31
    const int w0 = (tid & 7) << 1;
    const int g  = g0 + at;
    const int spec = species[g];

    const float rs0 = rs[(spec << 4) + w0];
    const float rs1 = rs[(spec << 4) + w0 + 1];
    const float ia0 = -10.0f * inta[(spec << 4) + w0];
    const float ia1 = -10.0f * inta[(spec << 4) + w0 + 1];

    float acc0 = 0.0f, acc1 = 0.0f;
    #pragma unroll
    for (int s = 0; s < NSPLIT; ++s) {
        const unsigned off0 = sofs[s][0];
        unsigned lo = runbase[s] + (sofs[s][at]     - off0);
        unsigned hi = runbase[s] + (sofs[s][at + 1] - off0);
        if (hi > SLAB_CAP) hi = SLAB_CAP;
        if (lo > hi) lo = hi;
        for (unsigned k = lo; k < hi; ++k) {
            const unsigned v = slab[k];      // 8-lane same-address broadcast
            const float r   = (float)(v & 0xFFFFu) * DEC_SCALE;
            const float fcv = (float)(v >> 16) * FC_DEC;
            const float d0 = r - rs0;
            const float d1 = r - rs1;
            acc0 = fmaf(fcv, __expf(ia0 * d0 * d0), acc0);
            acc1 = fmaf(fcv, __expf(ia1 * d1 * d1), acc1);
        }
    }

    const float2 sq = make_float2(acc0 * acc0, acc1 * acc1);
    const float2 zero = make_float2(0.f, 0.f);
    float* orow = out + (size_t)g * (NTYPE * NWAVE) + w0;
    #pragma unroll
    for (int ty = 0; ty < NTYPE; ++ty)
        *reinterpret_cast<float2*>(orow + ty * NWAVE) = (ty == spec) ? sq : zero;
}

// ---------------------------------------------------------------------------
// Fallback path (ws too small): global-atomic version (no workspace needed).
// ---------------------------------------------------------------------------
__global__ __launch_bounds__(256) void radial_pair_atomic(
    const float* __restrict__ coords, const float* __restrict__ shifts,
    const float* __restrict__ rs, const float* __restrict__ inta,
    const int* __restrict__ atom_index, const int* __restrict__ species,
    float* __restrict__ dens)
{
    int p = blockIdx.x * blockDim.x + threadIdx.x;
    if (p >= NPAIRS) return;
    int b  = p >> 16;
    int pp = p & (PPB - 1);
    int i = atom_index[(b * 2 + 0) * PPB + pp] + b * NA;
    int j = atom_index[(b * 2 + 1) * PPB + pp] + b * NA;
    float sx = shifts[p * 3 + 0], sy = shifts[p * 3 + 1], sz = shifts[p * 3 + 2];
    bool valid = (sx > -1e9f) && (sy > -1e9f) && (sz > -1e9f);
    float dx = coords[i * 3 + 0] - coords[j * 3 + 0] + sx;
    float dy = coords[i * 3 + 1] - coords[j * 3 + 1] + sy;
    float dz = coords[i * 3 + 2] - coords[j * 3 + 2] + sz;
    float r  = sqrtf(dx * dx + dy * dy + dz * dz);
    int spec = species[i];
    float x  = fminf(r * CUTOFF_INV, 1.0f);
    float fc = 0.5f * (__cosf(x * PI_F) + 1.0f);
    if (!valid) fc = 0.0f;
    const float* rsrow   = rs   + spec * NWAVE;
    const float* intarow = inta + spec * NWAVE;
    float* dst = dens + ((size_t)i * NTYPE + spec) * NWAVE;
    #pragma unroll
    for (int w = 0; w < NWAVE; ++w) {
        float d   = r - rsrow[w];
        float val = fc * __expf(-10.0f * intarow[w] * d * d);
        atomicAdd(dst + w, val);
    }
}

__global__ __launch_bounds__(256) void square_kernel(float* __restrict__ out)
{
    int i = blockIdx.x * blockDim.x + threadIdx.x;
    if (i * 4 >= DENS_ELEMS) return;
    float4* p = reinterpret_cast<float4*>(out) + i;
    float4 v = *p;
    v.x *= v.x; v.y *= v.y; v.z *= v.z; v.w *= v.w;
    *p = v;
}

extern "C" void kernel_launch(void* const* d_in, const int* in_sizes, int n_in,
                              void* d_out, int out_size, void* d_ws, size_t ws_size,
                              hipStream_t stream) {
    const float* coords     = (const float*)d_in[0];
    const float* shifts     = (const float*)d_in[1];
    const float* rs         = (const float*)d_in[2];
    const float* inta       = (const float*)d_in[3];
    const int*   atom_index = (const int*)d_in[6];
    const int*   species    = (const int*)d_in[7];
    float* out = (float*)d_out;

    if (ws_size >= WS2_NEEDED) {
        unsigned* csr  = (unsigned*)d_ws;
        unsigned* offs = (unsigned*)((char*)d_ws + CSR_BYTES);

        radial_bin_csr<<<dim3(NSEG), dim3(BLOCK_A), 0, stream>>>(
            coords, shifts, atom_index, csr, offs);
        radial_gather_slab<<<dim3(TOTATOM / APB), dim3(GBLOCK), 0, stream>>>(
            csr, offs, rs, inta, species, out);
    } else {
        hipMemsetAsync(d_out, 0, (size_t)DENS_ELEMS * sizeof(float), stream);
        radial_pair_atomic<<<dim3((NPAIRS + 255) / 256), dim3(256), 0, stream>>>(
            coords, shifts, rs, inta, atom_index, species, out);
        square_kernel<<<dim3((DENS_ELEMS / 4 + 255) / 256), dim3(256), 0, stream>>>(out);
    }
}

// Round 21
// 34.607 us; speedup vs baseline: 2.0816x; 1.1064x over previous
//
#include <hip/hip_runtime.h>
#include <math.h>

// Problem constants (fixed by the reference setup)
#define NB     32
#define NA     1024
#define NTYPE  4
#define NWAVE  16
#define PPB    65536               // pairs per batch
#define NPAIRS (NB * PPB)          // 2,097,152 pairs
#define TOTATOM (NB * NA)          // 32768
#define DENS_ELEMS (TOTATOM * NTYPE * NWAVE)  // == out_size
#define CUTOFF      5.0f
#define CUTOFF_INV  0.2f
#define PI_F 3.14159265358979323846f
#define LOG2E 1.4426950408889634f

#define NSPLIT 8                   // bin blocks per batch
#define BLOCK_A 1024
#define PPBLK (PPB / NSPLIT)       // 8192 pairs per bin-block
#define KITERS_A (PPBLK / BLOCK_A) // 8
#define NSEG (NB * NSPLIT)         // 256 CSR segments
#define ENC_SCALE (65535.0f / CUTOFF)
#define DEC_SCALE (CUTOFF / 65535.0f)
#define FC_ENC 65535.0f
#define FC_DEC (1.0f / 65535.0f)

#define CSR_BYTES  ((size_t)NSEG * PPBLK * 4)        // 8 MiB (packed u32)
#define OFFS_U32S  ((size_t)NSEG * (NA + 1))         // 262,400
#define WS2_NEEDED (CSR_BYTES + OFFS_U32S * 4)       // ~9.4 MB

// Gather geometry: 32 consecutive atoms/block, 8 threads (w-pairs)/atom.
#define GBLOCK 256
#define APB    32
#define SLAB_CAP 2432              // words; block total ~Poisson(1962), +10.6 sd

// Compiler-visible native LDS u32 atomic add (returns old).
typedef __attribute__((address_space(3))) unsigned lds_u32;
__device__ __forceinline__ unsigned lds_uinc(unsigned* p) {
    lds_u32* lp = (lds_u32*)(unsigned)(unsigned long long)p;
    return __atomic_fetch_add(lp, 1u, __ATOMIC_RELAXED);
}

// ---------------------------------------------------------------------------
// Phase A (identical to round 15): r + fc once per pair; LDS histogram rank;
// block prefix-scan -> exact CSR (sorted by atom within segment); coalesced out.
// ---------------------------------------------------------------------------
__global__ __launch_bounds__(BLOCK_A) void radial_bin_csr(
    const float* __restrict__ coords,      // [TOTATOM*3]
    const float* __restrict__ shifts,      // [NPAIRS*3]
    const int*   __restrict__ atom_index,  // [NB*2*PPB]
    unsigned*    __restrict__ csr,         // [NSEG][PPBLK] packed
    unsigned*    __restrict__ offs)        // [NSEG][NA+1]
{
    __shared__ unsigned hist[NA];            // 4 KiB
    __shared__ unsigned base[NA + 1];        // 4 KiB
    __shared__ unsigned wsum[16];
    __shared__ unsigned scsr[PPBLK];         // 32 KiB

    const int b    = blockIdx.x >> 3;        // / NSPLIT
    const int s    = blockIdx.x & (NSPLIT - 1);
    const int seg  = b * NSPLIT + s;
    const int tid  = threadIdx.x;
    const int lane = tid & 63;
    const int wid  = tid >> 6;

    hist[tid] = 0u;
    __syncthreads();

    const int* ai0 = atom_index + (b * 2 + 0) * PPB + s * PPBLK;
    const int* ai1 = atom_index + (b * 2 + 1) * PPB + s * PPBLK;
    const float* cb  = coords + (size_t)b * NA * 3;
    const float* shb = shifts + ((size_t)b * PPB + s * PPBLK) * 3;

    int      ik[KITERS_A];   // center atom, -1 if dropped
    unsigned rk[KITERS_A];   // rank from histogram atomic
    unsigned ek[KITERS_A];   // packed (fc_u16 << 16) | r_u16

    #pragma unroll
    for (int k = 0; k < KITERS_A; ++k) {
        const int pp = k * BLOCK_A + tid;
        const int i = ai0[pp];
        const int j = ai1[pp];

        const float sx = shb[pp * 3 + 0];
        const float sy = shb[pp * 3 + 1];
        const float sz = shb[pp * 3 + 2];
        const bool valid = (sx > -1e9f) && (sy > -1e9f) && (sz > -1e9f);

        const float dx = cb[i * 3 + 0] - cb[j * 3 + 0] + sx;
        const float dy = cb[i * 3 + 1] - cb[j * 3 + 1] + sy;
        const float dz = cb[i * 3 + 2] - cb[j * 3 + 2] + sz;
        const float r  = sqrtf(dx * dx + dy * dy + dz * dz);

        // r >= CUTOFF -> fc == 0 exactly: drop. invalid -> drop.
        if (valid && r < CUTOFF) {
            const unsigned rank = lds_uinc(&hist[i]);   // ds_add_rtn_u32
            unsigned e = (unsigned)(r * ENC_SCALE + 0.5f);
            if (e > 65535u) e = 65535u;
            const float fc = 0.5f * (__cosf(r * (PI_F * CUTOFF_INV)) + 1.0f);
            unsigned fq = (unsigned)(fc * FC_ENC + 0.5f);
            if (fq > 65535u) fq = 65535u;
            ik[k] = i;
            rk[k] = rank;
            ek[k] = (fq << 16) | e;
        } else {
            ik[k] = -1;
            rk[k] = 0u;
            ek[k] = 0u;
        }
    }
    __syncthreads();

    // Block-wide exclusive prefix scan of hist[1024].
    const unsigned h = hist[tid];
    unsigned x = h;
    #pragma unroll
    for (int d = 1; d < 64; d <<= 1) {
        const unsigned v = __shfl_up(x, d);
        if (lane >= d) x += v;
    }
    if (lane == 63) wsum[wid] = x;
    __syncthreads();
    if (tid < 16) {
        const unsigned own = wsum[tid];
        unsigned y = own;
        #pragma unroll
        for (int d = 1; d < 16; d <<= 1) {
            const unsigned v = __shfl_up(y, d);
            if (lane >= d) y += v;
        }
        wsum[tid] = y - own;     // exclusive wave prefix
    }
    __syncthreads();
    const unsigned incl = x + wsum[wid];
    base[tid] = incl - h;
    if (tid == BLOCK_A - 1) base[NA] = incl;
    __syncthreads();

    // Pass 2: place each pair at base[atom] + rank inside LDS CSR.
    #pragma unroll
    for (int k = 0; k < KITERS_A; ++k) {
        if (ik[k] >= 0) {
            scsr[base[ik[k]] + rk[k]] = ek[k];
        }
    }
    __syncthreads();

    // Stream out coalesced.
    {
        const uint4* src = reinterpret_cast<const uint4*>(scsr);
        uint4* dst = reinterpret_cast<uint4*>(csr + (size_t)seg * PPBLK);
        #pragma unroll
        for (int k = 0; k < PPBLK / 4 / BLOCK_A; ++k)
            dst[k * BLOCK_A + tid] = src[k * BLOCK_A + tid];
    }
    unsigned* og = offs + (size_t)seg * (NA + 1);
    og[tid] = base[tid];
    if (tid == 0) og[NA] = base[NA];
}

// ---------------------------------------------------------------------------
// Phase B: bulk-copy slab (coalesced) + LDS->LDS repack into per-atom
// concatenated, pre-decoded float2 -> single clean compute loop per thread.
// ---------------------------------------------------------------------------
__global__ __launch_bounds__(GBLOCK) void radial_gather_repack(
    const unsigned* __restrict__ csr,    // [NSEG][PPBLK] packed
    const unsigned* __restrict__ offs,   // [NSEG][NA+1]
    const float* __restrict__ rs,        // [NTYPE*NWAVE]
    const float* __restrict__ inta,      // [NTYPE*NWAVE]
    const int*   __restrict__ species,   // [TOTATOM]
    float*       __restrict__ out)       // [TOTATOM][NTYPE*NWAVE]
{
    __shared__ unsigned slab[SLAB_CAP];          // 9.5 KiB raw entries
    __shared__ float2   concat[SLAB_CAP];        // 19 KiB decoded, atom-major
    __shared__ unsigned sofs[NSPLIT][APB + 1];   // 1.03 KiB
    __shared__ unsigned runbase[NSPLIT];
    __shared__ unsigned tots[APB];
    __shared__ unsigned atomCat[APB + 1];

    const int tid = threadIdx.x;
    const int g0  = blockIdx.x * APB;        // first atom of block
    const int b   = g0 >> 10;                // batch (APB | NA -> no crossing)
    const int a0  = g0 & (NA - 1);

    // ---- 1. Load the 8x33 offset window (coalesced) ----
    for (int idx = tid; idx < NSPLIT * (APB + 1); idx += GBLOCK) {
        const int s = idx / (APB + 1);
        const int a = idx - s * (APB + 1);
        sofs[s][a] = offs[(size_t)(b * NSPLIT + s) * (NA + 1) + a0 + a];
    }
    __syncthreads();

    // ---- 2. runbase (serial, tiny) + per-(atom,seg) counts & 8-lane scan ----
    if (tid == 0) {
        unsigned acc = 0;
        #pragma unroll
        for (int s = 0; s < NSPLIT; ++s) {
            runbase[s] = acc;
            acc += sofs[s][APB] - sofs[s][0];
        }
    }
    const int rat = tid >> 3;                // repack atom 0..31
    const int rs8 = tid & 7;                 // repack seg 0..7
    const unsigned cnt = sofs[rs8][rat + 1] - sofs[rs8][rat];
    unsigned xin = cnt;
    #pragma unroll
    for (int d = 1; d < 8; d <<= 1) {
        const unsigned v = __shfl_up(xin, d, 8);
        if (rs8 >= d) xin += v;
    }
    const unsigned segPfx = xin - cnt;       // excl. prefix of cnt over segs
    if (rs8 == 7) tots[rat] = xin;           // per-atom total
    __syncthreads();

    // ---- 3. Bulk copy: 8 groups of 32 lanes, one contiguous run each ----
    {
        const int s = tid >> 5;
        const int l = tid & 31;
        const unsigned lo  = sofs[s][0];
        const unsigned len = sofs[s][APB] - lo;
        const unsigned* src = csr + (size_t)(b * NSPLIT + s) * PPBLK + lo;
        const unsigned bse = runbase[s];
        for (unsigned k = l; k < len; k += 32) {
            const unsigned p = bse + k;
            if (p < SLAB_CAP) slab[p] = src[k];
        }
    }
    __syncthreads();

    // ---- 4. 32-lane exclusive scan of per-atom totals ----
    if (tid < 32) {
        const unsigned t = tots[tid];
        unsigned x = t;
        #pragma unroll
        for (int d = 1; d < 32; d <<= 1) {
            const unsigned v = __shfl_up(x, d, 32);
            if (tid >= d) x += v;
        }
        atomCat[tid] = x - t;
        if (tid == 31) atomCat[32] = x;
    }
    __syncthreads();

    // ---- 5. Repack slab -> concat (atom-major), decode to float2 ----
    {
        const unsigned src0 = runbase[rs8] + (sofs[rs8][rat] - sofs[rs8][0]);
        const unsigned dst0 = atomCat[rat] + segPfx;
        for (unsigned k = 0; k < cnt; ++k) {
            const unsigned sp = src0 + k;
            const unsigned dp = dst0 + k;
            if (sp < SLAB_CAP && dp < SLAB_CAP) {
                const unsigned v = slab[sp];
                concat[dp] = make_float2((float)(v & 0xFFFFu) * DEC_SCALE,
                                         (float)(v >> 16) * FC_DEC);
            }
        }
    }
    __syncthreads();

    // ---- 6. Compute: thread = (atom, w-pair), ONE loop over concat range ----
    const int at = tid >> 3;
    const int w0 = (tid & 7) << 1;
    const int g  = g0 + at;
    const int spec = species[g];

    const float rs0 = rs[(spec << 4) + w0];
    const float rs1 = rs[(spec << 4) + w0 + 1];
    // fold -10*inta and log2(e) into one constant; use native exp2
    const float ia0 = -10.0f * LOG2E * inta[(spec << 4) + w0];
    const float ia1 = -10.0f * LOG2E * inta[(spec << 4) + w0 + 1];

    const unsigned lo = atomCat[at];
    unsigned hi = atomCat[at + 1];
    if (hi > SLAB_CAP) hi = SLAB_CAP;

    float acc0 = 0.0f, acc1 = 0.0f;
    for (unsigned k = lo; k < hi; ++k) {
        const float2 e = concat[k];          // 8-lane same-address broadcast
        const float d0 = e.x - rs0;
        const float d1 = e.x - rs1;
        acc0 = fmaf(e.y, __builtin_amdgcn_exp2f(ia0 * d0 * d0), acc0);
        acc1 = fmaf(e.y, __builtin_amdgcn_exp2f(ia1 * d1 * d1), acc1);
    }

    const float2 sq = make_float2(acc0 * acc0, acc1 * acc1);
    const float2 zero = make_float2(0.f, 0.f);
    float* orow = out + (size_t)g * (NTYPE * NWAVE) + w0;
    #pragma unroll
    for (int ty = 0; ty < NTYPE; ++ty)
        *reinterpret_cast<float2*>(orow + ty * NWAVE) = (ty == spec) ? sq : zero;
}

// ---------------------------------------------------------------------------
// Fallback path (ws too small): global-atomic version (no workspace needed).
// ---------------------------------------------------------------------------
__global__ __launch_bounds__(256) void radial_pair_atomic(
    const float* __restrict__ coords, const float* __restrict__ shifts,
    const float* __restrict__ rs, const float* __restrict__ inta,
    const int* __restrict__ atom_index, const int* __restrict__ species,
    float* __restrict__ dens)
{
    int p = blockIdx.x * blockDim.x + threadIdx.x;
    if (p >= NPAIRS) return;
    int b  = p >> 16;
    int pp = p & (PPB - 1);
    int i = atom_index[(b * 2 + 0) * PPB + pp] + b * NA;
    int j = atom_index[(b * 2 + 1) * PPB + pp] + b * NA;
    float sx = shifts[p * 3 + 0], sy = shifts[p * 3 + 1], sz = shifts[p * 3 + 2];
    bool valid = (sx > -1e9f) && (sy > -1e9f) && (sz > -1e9f);
    float dx = coords[i * 3 + 0] - coords[j * 3 + 0] + sx;
    float dy = coords[i * 3 + 1] - coords[j * 3 + 1] + sy;
    float dz = coords[i * 3 + 2] - coords[j * 3 + 2] + sz;
    float r  = sqrtf(dx * dx + dy * dy + dz * dz);
    int spec = species[i];
    float x  = fminf(r * CUTOFF_INV, 1.0f);
    float fc = 0.5f * (__cosf(x * PI_F) + 1.0f);
    if (!valid) fc = 0.0f;
    const float* rsrow   = rs   + spec * NWAVE;
    const float* intarow = inta + spec * NWAVE;
    float* dst = dens + ((size_t)i * NTYPE + spec) * NWAVE;
    #pragma unroll
    for (int w = 0; w < NWAVE; ++w) {
        float d   = r - rsrow[w];
        float val = fc * __expf(-10.0f * intarow[w] * d * d);
        atomicAdd(dst + w, val);
    }
}

__global__ __launch_bounds__(256) void square_kernel(float* __restrict__ out)
{
    int i = blockIdx.x * blockDim.x + threadIdx.x;
    if (i * 4 >= DENS_ELEMS) return;
    float4* p = reinterpret_cast<float4*>(out) + i;
    float4 v = *p;
    v.x *= v.x; v.y *= v.y; v.z *= v.z; v.w *= v.w;
    *p = v;
}

extern "C" void kernel_launch(void* const* d_in, const int* in_sizes, int n_in,
                              void* d_out, int out_size, void* d_ws, size_t ws_size,
                              hipStream_t stream) {
    const float* coords     = (const float*)d_in[0];
    const float* shifts     = (const float*)d_in[1];
    const float* rs         = (const float*)d_in[2];
    const float* inta       = (const float*)d_in[3];
    const int*   atom_index = (const int*)d_in[6];
    const int*   species    = (const int*)d_in[7];
    float* out = (float*)d_out;

    if (ws_size >= WS2_NEEDED) {
        unsigned* csr  = (unsigned*)d_ws;
        unsigned* offs = (unsigned*)((char*)d_ws + CSR_BYTES);

        radial_bin_csr<<<dim3(NSEG), dim3(BLOCK_A), 0, stream>>>(
            coords, shifts, atom_index, csr, offs);
        radial_gather_repack<<<dim3(TOTATOM / APB), dim3(GBLOCK), 0, stream>>>(
            csr, offs, rs, inta, species, out);
    } else {
        hipMemsetAsync(d_out, 0, (size_t)DENS_ELEMS * sizeof(float), stream);
        radial_pair_atomic<<<dim3((NPAIRS + 255) / 256), dim3(256), 0, stream>>>(
            coords, shifts, rs, inta, atom_index, species, out);
        square_kernel<<<dim3((DENS_ELEMS / 4 + 255) / 256), dim3(256), 0, stream>>>(out);
    }
}

// Round 22
// 33.210 us; speedup vs baseline: 2.1692x; 1.0421x over previous
//
#include <hip/hip_runtime.h>
#include <math.h>

// Problem constants (fixed by the reference setup)
#define NB     32
#define NA     1024
#define NTYPE  4
#define NWAVE  16
#define PPB    65536               // pairs per batch
#define NPAIRS (NB * PPB)          // 2,097,152 pairs
#define TOTATOM (NB * NA)          // 32768
#define DENS_ELEMS (TOTATOM * NTYPE * NWAVE)  // == out_size
#define CUTOFF      5.0f
#define CUTOFF_INV  0.2f
#define PI_F 3.14159265358979323846f
#define LOG2E 1.4426950408889634f

#define NSPLIT 8                   // bin blocks per batch
#define BLOCK_A 1024
#define PPBLK (PPB / NSPLIT)       // 8192 pairs per bin-block
#define KITERS_A (PPBLK / BLOCK_A) // 8
#define NSEG (NB * NSPLIT)         // 256 CSR segments
#define ENC_SCALE (65535.0f / CUTOFF)
#define DEC_SCALE (CUTOFF / 65535.0f)
#define FC_ENC 65535.0f
#define FC_DEC (1.0f / 65535.0f)

#define CSR_BYTES  ((size_t)NSEG * PPBLK * 4)        // 8 MiB (packed u32)
#define OFFS_U32S  ((size_t)NSEG * (NA + 1))         // 262,400
#define WS2_NEEDED (CSR_BYTES + OFFS_U32S * 4)       // ~9.4 MB

// Gather geometry: 32 consecutive atoms/block, 8 threads (w-pairs)/atom.
#define GBLOCK 256
#define APB    32
#define SLAB_CAP 2432              // words; block total ~Poisson(1962), +10.6 sd

// Compiler-visible native LDS u32 atomic add (returns old).
typedef __attribute__((address_space(3))) unsigned lds_u32;
__device__ __forceinline__ unsigned lds_uinc(unsigned* p) {
    lds_u32* lp = (lds_u32*)(unsigned)(unsigned long long)p;
    return __atomic_fetch_add(lp, 1u, __ATOMIC_RELAXED);
}

// ---------------------------------------------------------------------------
// Phase A (identical to round 15): r + fc once per pair; LDS histogram rank;
// block prefix-scan -> exact CSR (sorted by atom within segment); coalesced out.
// ---------------------------------------------------------------------------
__global__ __launch_bounds__(BLOCK_A) void radial_bin_csr(
    const float* __restrict__ coords,      // [TOTATOM*3]
    const float* __restrict__ shifts,      // [NPAIRS*3]
    const int*   __restrict__ atom_index,  // [NB*2*PPB]
    unsigned*    __restrict__ csr,         // [NSEG][PPBLK] packed
    unsigned*    __restrict__ offs)        // [NSEG][NA+1]
{
    __shared__ unsigned hist[NA];            // 4 KiB
    __shared__ unsigned base[NA + 1];        // 4 KiB
    __shared__ unsigned wsum[16];
    __shared__ unsigned scsr[PPBLK];         // 32 KiB

    const int b    = blockIdx.x >> 3;        // / NSPLIT
    const int s    = blockIdx.x & (NSPLIT - 1);
    const int seg  = b * NSPLIT + s;
    const int tid  = threadIdx.x;
    const int lane = tid & 63;
    const int wid  = tid >> 6;

    hist[tid] = 0u;
    __syncthreads();

    const int* ai0 = atom_index + (b * 2 + 0) * PPB + s * PPBLK;
    const int* ai1 = atom_index + (b * 2 + 1) * PPB + s * PPBLK;
    const float* cb  = coords + (size_t)b * NA * 3;
    const float* shb = shifts + ((size_t)b * PPB + s * PPBLK) * 3;

    int      ik[KITERS_A];   // center atom, -1 if dropped
    unsigned rk[KITERS_A];   // rank from histogram atomic
    unsigned ek[KITERS_A];   // packed (fc_u16 << 16) | r_u16

    #pragma unroll
    for (int k = 0; k < KITERS_A; ++k) {
        const int pp = k * BLOCK_A + tid;
        const int i = ai0[pp];
        const int j = ai1[pp];

        const float sx = shb[pp * 3 + 0];
        const float sy = shb[pp * 3 + 1];
        const float sz = shb[pp * 3 + 2];
        const bool valid = (sx > -1e9f) && (sy > -1e9f) && (sz > -1e9f);

        const float dx = cb[i * 3 + 0] - cb[j * 3 + 0] + sx;
        const float dy = cb[i * 3 + 1] - cb[j * 3 + 1] + sy;
        const float dz = cb[i * 3 + 2] - cb[j * 3 + 2] + sz;
        const float r  = sqrtf(dx * dx + dy * dy + dz * dz);

        // r >= CUTOFF -> fc == 0 exactly: drop. invalid -> drop.
        if (valid && r < CUTOFF) {
            const unsigned rank = lds_uinc(&hist[i]);   // ds_add_rtn_u32
            unsigned e = (unsigned)(r * ENC_SCALE + 0.5f);
            if (e > 65535u) e = 65535u;
            const float fc = 0.5f * (__cosf(r * (PI_F * CUTOFF_INV)) + 1.0f);
            unsigned fq = (unsigned)(fc * FC_ENC + 0.5f);
            if (fq > 65535u) fq = 65535u;
            ik[k] = i;
            rk[k] = rank;
            ek[k] = (fq << 16) | e;
        } else {
            ik[k] = -1;
            rk[k] = 0u;
            ek[k] = 0u;
        }
    }
    __syncthreads();

    // Block-wide exclusive prefix scan of hist[1024].
    const unsigned h = hist[tid];
    unsigned x = h;
    #pragma unroll
    for (int d = 1; d < 64; d <<= 1) {
        const unsigned v = __shfl_up(x, d);
        if (lane >= d) x += v;
    }
    if (lane == 63) wsum[wid] = x;
    __syncthreads();
    if (tid < 16) {
        const unsigned own = wsum[tid];
        unsigned y = own;
        #pragma unroll
        for (int d = 1; d < 16; d <<= 1) {
            const unsigned v = __shfl_up(y, d);
            if (lane >= d) y += v;
        }
        wsum[tid] = y - own;     // exclusive wave prefix
    }
    __syncthreads();
    const unsigned incl = x + wsum[wid];
    base[tid] = incl - h;
    if (tid == BLOCK_A - 1) base[NA] = incl;
    __syncthreads();

    // Pass 2: place each pair at base[atom] + rank inside LDS CSR.
    #pragma unroll
    for (int k = 0; k < KITERS_A; ++k) {
        if (ik[k] >= 0) {
            scsr[base[ik[k]] + rk[k]] = ek[k];
        }
    }
    __syncthreads();

    // Stream out coalesced.
    {
        const uint4* src = reinterpret_cast<const uint4*>(scsr);
        uint4* dst = reinterpret_cast<uint4*>(csr + (size_t)seg * PPBLK);
        #pragma unroll
        for (int k = 0; k < PPBLK / 4 / BLOCK_A; ++k)
            dst[k * BLOCK_A + tid] = src[k * BLOCK_A + tid];
    }
    unsigned* og = offs + (size_t)seg * (NA + 1);
    og[tid] = base[tid];
    if (tid == 0) og[NA] = base[NA];
}

// ---------------------------------------------------------------------------
// Phase B: bulk-copy slab + repack to per-atom concatenated float2, then a
// 4x-UNROLLED compute loop (even-aligned -> ds_read_b128 pairs, 4 indep exp
// chains, split accumulators) to break the per-iteration LDS latency chain.
// ---------------------------------------------------------------------------
__global__ __launch_bounds__(GBLOCK) void radial_gather_repack4(
    const unsigned* __restrict__ csr,    // [NSEG][PPBLK] packed
    const unsigned* __restrict__ offs,   // [NSEG][NA+1]
    const float* __restrict__ rs,        // [NTYPE*NWAVE]
    const float* __restrict__ inta,      // [NTYPE*NWAVE]
    const int*   __restrict__ species,   // [TOTATOM]
    float*       __restrict__ out)       // [TOTATOM][NTYPE*NWAVE]
{
    __shared__ unsigned slab[SLAB_CAP];          // 9.5 KiB raw entries
    __shared__ float2   concat[SLAB_CAP];        // 19 KiB decoded, atom-major
    __shared__ unsigned sofs[NSPLIT][APB + 1];   // 1.03 KiB
    __shared__ unsigned runbase[NSPLIT];
    __shared__ unsigned tots[APB];
    __shared__ unsigned atomCat[APB + 1];

    const int tid = threadIdx.x;
    const int g0  = blockIdx.x * APB;        // first atom of block
    const int b   = g0 >> 10;                // batch (APB | NA -> no crossing)
    const int a0  = g0 & (NA - 1);

    // ---- 1. Load the 8x33 offset window (coalesced) ----
    for (int idx = tid; idx < NSPLIT * (APB + 1); idx += GBLOCK) {
        const int s = idx / (APB + 1);
        const int a = idx - s * (APB + 1);
        sofs[s][a] = offs[(size_t)(b * NSPLIT + s) * (NA + 1) + a0 + a];
    }
    __syncthreads();

    // ---- 2. runbase + per-(atom,seg) counts, 8-lane scan, atom totals ----
    if (tid == 0) {
        unsigned acc = 0;
        #pragma unroll
        for (int s = 0; s < NSPLIT; ++s) {
            runbase[s] = acc;
            acc += sofs[s][APB] - sofs[s][0];
        }
    }
    const int rat = tid >> 3;                // repack atom 0..31
    const int rs8 = tid & 7;                 // repack seg 0..7
    const unsigned cnt = sofs[rs8][rat + 1] - sofs[rs8][rat];
    unsigned xin = cnt;
    #pragma unroll
    for (int d = 1; d < 8; d <<= 1) {
        const unsigned v = __shfl_up(xin, d, 8);
        if (rs8 >= d) xin += v;
    }
    const unsigned segPfx = xin - cnt;       // excl. prefix of cnt over segs
    if (rs8 == 7) tots[rat] = xin;           // per-atom total
    __syncthreads();

    // ---- 3. 32-lane scan of totals (independent of copy) + bulk copy ----
    if (tid < 32) {
        const unsigned t = tots[tid];
        unsigned x = t;
        #pragma unroll
        for (int d = 1; d < 32; d <<= 1) {
            const unsigned v = __shfl_up(x, d, 32);
            if (tid >= d) x += v;
        }
        atomCat[tid] = x - t;
        if (tid == 31) atomCat[32] = x;
    }
    {
        const int s = tid >> 5;
        const int l = tid & 31;
        const unsigned lo  = sofs[s][0];
        const unsigned len = sofs[s][APB] - lo;
        const unsigned* src = csr + (size_t)(b * NSPLIT + s) * PPBLK + lo;
        const unsigned bse = runbase[s];
        for (unsigned k = l; k < len; k += 32) {
            const unsigned p = bse + k;
            if (p < SLAB_CAP) slab[p] = src[k];
        }
    }
    __syncthreads();

    // ---- 4. Repack slab -> concat (atom-major), decode to float2 ----
    {
        const unsigned src0 = runbase[rs8] + (sofs[rs8][rat] - sofs[rs8][0]);
        const unsigned dst0 = atomCat[rat] + segPfx;
        for (unsigned k = 0; k < cnt; ++k) {
            const unsigned sp = src0 + k;
            const unsigned dp = dst0 + k;
            if (sp < SLAB_CAP && dp < SLAB_CAP) {
                const unsigned v = slab[sp];
                concat[dp] = make_float2((float)(v & 0xFFFFu) * DEC_SCALE,
                                         (float)(v >> 16) * FC_DEC);
            }
        }
    }
    __syncthreads();

    // ---- 5. Compute: thread = (atom, w-pair), 4x-unrolled over concat ----
    const int at = tid >> 3;
    const int w0 = (tid & 7) << 1;
    const int g  = g0 + at;
    const int spec = species[g];

    const float rs0 = rs[(spec << 4) + w0];
    const float rs1 = rs[(spec << 4) + w0 + 1];
    const float ia0 = -10.0f * LOG2E * inta[(spec << 4) + w0];
    const float ia1 = -10.0f * LOG2E * inta[(spec << 4) + w0 + 1];

    unsigned k  = atomCat[at];
    unsigned hi = atomCat[at + 1];
    if (hi > SLAB_CAP) hi = SLAB_CAP;
    if (k > hi) k = hi;

    float A0 = 0.f, B0 = 0.f, A1 = 0.f, B1 = 0.f;   // split accumulators

    #define BODY(E, ACC0, ACC1)                                          \
    {                                                                    \
        const float d0 = (E).x - rs0;                                    \
        const float d1 = (E).x - rs1;                                    \
        ACC0 = fmaf((E).y, __builtin_amdgcn_exp2f(ia0 * d0 * d0), ACC0); \
        ACC1 = fmaf((E).y, __builtin_amdgcn_exp2f(ia1 * d1 * d1), ACC1); \
    }

    // Prologue: align k to even (16B) boundary for b128-pairable reads.
    if ((k & 1u) && k < hi) { const float2 e = concat[k]; BODY(e, A0, A1) ++k; }

    // Main: 4 entries/iter; reads issued as two contiguous float2-pairs.
    for (; k + 4 <= hi; k += 4) {
        const float2 e0 = concat[k + 0];
        const float2 e1 = concat[k + 1];
        const float2 e2 = concat[k + 2];
        const float2 e3 = concat[k + 3];
        BODY(e0, A0, A1) BODY(e1, B0, B1)
        BODY(e2, A0, A1) BODY(e3, B0, B1)
    }
    // Tail (<4).
    for (; k < hi; ++k) { const float2 e = concat[k]; BODY(e, A0, A1) }
    #undef BODY

    const float s0 = A0 + B0, s1 = A1 + B1;
    const float2 sq = make_float2(s0 * s0, s1 * s1);
    const float2 zero = make_float2(0.f, 0.f);
    float* orow = out + (size_t)g * (NTYPE * NWAVE) + w0;
    #pragma unroll
    for (int ty = 0; ty < NTYPE; ++ty)
        *reinterpret_cast<float2*>(orow + ty * NWAVE) = (ty == spec) ? sq : zero;
}

// ---------------------------------------------------------------------------
// Fallback path (ws too small): global-atomic version (no workspace needed).
// ---------------------------------------------------------------------------
__global__ __launch_bounds__(256) void radial_pair_atomic(
    const float* __restrict__ coords, const float* __restrict__ shifts,
    const float* __restrict__ rs, const float* __restrict__ inta,
    const int* __restrict__ atom_index, const int* __restrict__ species,
    float* __restrict__ dens)
{
    int p = blockIdx.x * blockDim.x + threadIdx.x;
    if (p >= NPAIRS) return;
    int b  = p >> 16;
    int pp = p & (PPB - 1);
    int i = atom_index[(b * 2 + 0) * PPB + pp] + b * NA;
    int j = atom_index[(b * 2 + 1) * PPB + pp] + b * NA;
    float sx = shifts[p * 3 + 0], sy = shifts[p * 3 + 1], sz = shifts[p * 3 + 2];
    bool valid = (sx > -1e9f) && (sy > -1e9f) && (sz > -1e9f);
    float dx = coords[i * 3 + 0] - coords[j * 3 + 0] + sx;
    float dy = coords[i * 3 + 1] - coords[j * 3 + 1] + sy;
    float dz = coords[i * 3 + 2] - coords[j * 3 + 2] + sz;
    float r  = sqrtf(dx * dx + dy * dy + dz * dz);
    int spec = species[i];
    float x  = fminf(r * CUTOFF_INV, 1.0f);
    float fc = 0.5f * (__cosf(x * PI_F) + 1.0f);
    if (!valid) fc = 0.0f;
    const float* rsrow   = rs   + spec * NWAVE;
    const float* intarow = inta + spec * NWAVE;
    float* dst = dens + ((size_t)i * NTYPE + spec) * NWAVE;
    #pragma unroll
    for (int w = 0; w < NWAVE; ++w) {
        float d   = r - rsrow[w];
        float val = fc * __expf(-10.0f * intarow[w] * d * d);
        atomicAdd(dst + w, val);
    }
}

__global__ __launch_bounds__(256) void square_kernel(float* __restrict__ out)
{
    int i = blockIdx.x * blockDim.x + threadIdx.x;
    if (i * 4 >= DENS_ELEMS) return;
    float4* p = reinterpret_cast<float4*>(out) + i;
    float4 v = *p;
    v.x *= v.x; v.y *= v.y; v.z *= v.z; v.w *= v.w;
    *p = v;
}

extern "C" void kernel_launch(void* const* d_in, const int* in_sizes, int n_in,
                              void* d_out, int out_size, void* d_ws, size_t ws_size,
                              hipStream_t stream) {
    const float* coords     = (const float*)d_in[0];
    const float* shifts     = (const float*)d_in[1];
    const float* rs         = (const float*)d_in[2];
    const float* inta       = (const float*)d_in[3];
    const int*   atom_index = (const int*)d_in[6];
    const int*   species    = (const int*)d_in[7];
    float* out = (float*)d_out;

    if (ws_size >= WS2_NEEDED) {
        unsigned* csr  = (unsigned*)d_ws;
        unsigned* offs = (unsigned*)((char*)d_ws + CSR_BYTES);

        radial_bin_csr<<<dim3(NSEG), dim3(BLOCK_A), 0, stream>>>(
            coords, shifts, atom_index, csr, offs);
        radial_gather_repack4<<<dim3(TOTATOM / APB), dim3(GBLOCK), 0, stream>>>(
            csr, offs, rs, inta, species, out);
    } else {
        hipMemsetAsync(d_out, 0, (size_t)DENS_ELEMS * sizeof(float), stream);
        radial_pair_atomic<<<dim3((NPAIRS + 255) / 256), dim3(256), 0, stream>>>(
            coords, shifts, rs, inta, atom_index, species, out);
        square_kernel<<<dim3((DENS_ELEMS / 4 + 255) / 256), dim3(256), 0, stream>>>(out);
    }
}